// Round 4
// baseline (222.681 us; speedup 1.0000x reference)
//
#include <hip/hip_runtime.h>
#include <hip/hip_fp16.h>
#include <math.h>

// clDice loss on 32x1x512x512: sigmoid + dice + 10x soft-skeletonize + skel dice.
// R1: per-block partials (1059 -> 466 us). R3: fused 2 iters/kernel via LDS (485).
// R5: 256 thr/block (316). R7: fp16 ping-pong + fp16 LDS B (262).
// R9: packed fp16 stencil (v_pk_min/max), instrs down, dur flat (265).
// R10: 8-px quantum + 64x128 tile + EDGE templates (227).
// R11: DMA fill (global_load_lds) in k_mid/k_last, batched MLP fill in k_first
//      (k_first 65->43; total 220). Harness memset of 256MiB ws = ~42us, fixed cost.
// R12: hide fill latency at tile granularity (k_mid ~2.7x above roofline floors;
//      exposed DMA drain at the post-fill barrier is the gap):
//      - k_mid: 2 y-adjacent tiles per block; tile1's DMA issues right after
//        stage1(tile0)'s barrier (A dead), drains under stage2(tile0) compute +
//        global writes. Grid 1024 = exactly 4 blocks/CU, single residency round.
//      - k_last: target-tile DMA issues before stage2(pred) (same trick).

#define H 512
#define W 512
#define IMG (H * W)
#define NIMG 64
#define NPRED 32

#define APU 72      // A row pitch in uints (2 fp16/uint); uint u <-> tile cols (2u-8,2u-7)
#define AROWS 74    // row r <-> gy = tileY + r - 4; data rows 0..71 (72,73 pad)
#define BPU 68      // B row pitch in uints; uint u <-> tile cols (2u-4,2u-3)
#define BROWS 68    // row br <-> gy = tileY + br - 2
#define TQ 17       // stage1 col-groups (8 px each): output cols 8g-4..8g+3
#define S1ITEMS 238 // 14 strips x 17 groups
#define FILLN (AROWS * 18)  // 74 rows x 18 uint4-slots = 1332

#define PINF2 0x7C007C00u   // +inf,+inf (erosion-neutral pad)
#define NINF2 0xFC00FC00u   // -inf,-inf (dilation-neutral mask)
#define ONE2  0x3C003C00u   // 1.0,1.0

typedef _Float16 f16;
typedef _Float16 h2 __attribute__((ext_vector_type(2)));
typedef __fp16 fp16v2 __attribute__((ext_vector_type(2)));

__device__ __forceinline__ float2 unpack2(uint u) {
    fp16v2 h = __builtin_bit_cast(fp16v2, u);
    return make_float2((float)h.x, (float)h.y);
}
__device__ __forceinline__ uint pack2(float a, float b) {
    fp16v2 h = __builtin_amdgcn_cvt_pkrtz(a, b);
    return __builtin_bit_cast(uint, h);
}
__device__ __forceinline__ uint pmin(uint a, uint b) {
    uint d; asm("v_pk_min_f16 %0, %1, %2" : "=v"(d) : "v"(a), "v"(b)); return d;
}
__device__ __forceinline__ uint pmax(uint a, uint b) {
    uint d; asm("v_pk_max_f16 %0, %1, %2" : "=v"(d) : "v"(a), "v"(b)); return d;
}
// (hi<<16)|(lo>>16): odd-aligned fp16 pair from two even-aligned pairs
__device__ __forceinline__ uint abit(uint hi, uint lo) {
    return __builtin_amdgcn_alignbit(hi, lo, 16);
}

// async global->LDS DMA, 16B per lane. LDS dest must be wave-uniform base +
// lane*16, which our fill layout satisfies by construction.
__device__ __forceinline__ void lds_dma16(uint* l, const void* g) {
    __builtin_amdgcn_global_load_lds(
        (__attribute__((address_space(1))) void*)(g),
        (__attribute__((address_space(3))) void*)(l), 16, 0, 0);
}

__device__ __forceinline__ float wsum64(float v) {
#pragma unroll
    for (int o = 32; o > 0; o >>= 1) v += __shfl_down(v, o);
    return v;
}

// Horizontal 3-min at 6 aligned pairs (cols c0-2..c0+9) from 8 uints (cols
// c0-4..c0+11); p points at the uint 2 pairs left of the first output pair.
// Two ds_read_b128. Also returns center pairs sc (cols c0..c0+7).
__device__ __forceinline__ void hmin8p(const uint* __restrict__ p, uint m[6], uint sc[4]) {
    uint4 w0 = *(const uint4*)(p);
    uint4 w1 = *(const uint4*)(p + 4);
    uint w[8] = {w0.x, w0.y, w0.z, w0.w, w1.x, w1.y, w1.z, w1.w};
    sc[0] = w[2]; sc[1] = w[3]; sc[2] = w[4]; sc[3] = w[5];
    uint s[7];
#pragma unroll
    for (int j = 0; j < 7; j++) s[j] = abit(w[j + 1], w[j]);
#pragma unroll
    for (int i = 0; i < 6; i++) m[i] = pmin(s[i], pmin(w[i + 1], s[i + 1]));
}

// Vertical 3-min; EDGE adds center-out-of-image mask (-inf). Pairs are
// even-aligned and image x-bounds (0,512) are even, so masks are pair-uniform.
template<bool EDGE>
__device__ __forceinline__ void erode8(const uint a[6], const uint b[6], const uint c[6],
                                       bool rowok, const bool* eok, uint e[6]) {
#pragma unroll
    for (int i = 0; i < 6; i++) {
        uint v = pmin(a[i], pmin(b[i], c[i]));
        e[i] = EDGE ? ((rowok && eok[i]) ? v : NINF2) : v;
    }
}

// Horizontal 3-max at the 4 center pairs; ec = eroded center pairs.
__device__ __forceinline__ void hmax8(const uint e[6], uint hx[4], uint ec[4]) {
    uint a[5];
#pragma unroll
    for (int j = 0; j < 5; j++) a[j] = abit(e[j + 1], e[j]);
#pragma unroll
    for (int p = 0; p < 4; p++) {
        hx[p] = pmax(a[p], pmax(e[p + 1], a[p + 1]));
        ec[p] = e[p + 1];
    }
}

// skel update, packed fp16: o = clamp(s - (s-e)*t, 0, 1).
__device__ __forceinline__ uint upd_pair(uint s, uint ec, uint t) {
    h2 sh = __builtin_bit_cast(h2, s);
    h2 eh = __builtin_bit_cast(h2, ec);
    h2 th = __builtin_bit_cast(h2, t);
    h2 o = sh - (sh - eh) * th;           // v_pk_add + v_pk_fma
    return pmin(pmax(__builtin_bit_cast(uint, o), 0u), ONE2);
}

// Fill packed-fp16 LDS A from fp32 source (optional sigmoid); fuse dice
// partials over the 64x128 interior (fp32 pre-pack values -> exact dice).
// Batched 2 x 3: issue 3 items' loads (6-12 global loads) before consuming.
template<bool EDGE, int SIG>
__device__ float2 fillA_f32(uint* __restrict__ A, const float* __restrict__ src,
                            const float* __restrict__ tgt,
                            int tileX, int tileY, int tid) {
    float a = 0.0f, b = 0.0f;
#pragma unroll
    for (int hf = 0; hf < 2; hf++) {
        float4 v0[3], v1[3], t0[3], t1[3];
        bool ld[3];
#pragma unroll
        for (int j = 0; j < 3; j++) {
            const int i = tid + 256 * (3 * hf + j);
            const int r = i / 18;
            const int q = i - 18 * r;
            const int gy = tileY + r - 4;
            const int gx = tileX - 8 + 8 * q;
            bool ok = (i < FILLN);
            if (EDGE) ok = ok && (r < 72) && ((unsigned)gy < (unsigned)H) &&
                           ((unsigned)gx < (unsigned)W);
            ld[j] = ok;
            if (ok) {
                const float* sp = src + (size_t)gy * W + gx;
                v0[j] = *(const float4*)(sp);
                v1[j] = *(const float4*)(sp + 4);
                if (SIG) {
                    const float* tp = tgt + (size_t)gy * W + gx;
                    t0[j] = *(const float4*)(tp);
                    t1[j] = *(const float4*)(tp + 4);
                }
            }
        }
#pragma unroll
        for (int j = 0; j < 3; j++) {
            const int i = tid + 256 * (3 * hf + j);
            const int r = i / 18;
            const int q = i - 18 * r;
            if (i < FILLN) {
                uint4 w = make_uint4(PINF2, PINF2, PINF2, PINF2);
                if (ld[j]) {
                    float4 f0 = v0[j], f1 = v1[j];
                    if (SIG) {
                        f0.x = 1.0f / (1.0f + __expf(-f0.x));
                        f0.y = 1.0f / (1.0f + __expf(-f0.y));
                        f0.z = 1.0f / (1.0f + __expf(-f0.z));
                        f0.w = 1.0f / (1.0f + __expf(-f0.w));
                        f1.x = 1.0f / (1.0f + __expf(-f1.x));
                        f1.y = 1.0f / (1.0f + __expf(-f1.y));
                        f1.z = 1.0f / (1.0f + __expf(-f1.z));
                        f1.w = 1.0f / (1.0f + __expf(-f1.w));
                    }
                    if (((unsigned)(r - 4) < 64u) && ((unsigned)(q - 1) < 16u)) {
                        if (SIG) {
                            a += f0.x * t0[j].x + f0.y * t0[j].y + f0.z * t0[j].z +
                                 f0.w * t0[j].w + f1.x * t1[j].x + f1.y * t1[j].y +
                                 f1.z * t1[j].z + f1.w * t1[j].w;
                            b += f0.x + f0.y + f0.z + f0.w + f1.x + f1.y + f1.z + f1.w;
                        } else {
                            a += f0.x + f0.y + f0.z + f0.w + f1.x + f1.y + f1.z + f1.w;
                        }
                    }
                    w.x = pack2(f0.x, f0.y); w.y = pack2(f0.z, f0.w);
                    w.z = pack2(f1.x, f1.y); w.w = pack2(f1.z, f1.w);
                }
                *(uint4*)(A + r * APU + 4 * q) = w;
            }
        }
    }
    return make_float2(a, b);
}

// DMA fill from fp16 buffer. Source addresses clamped into the image
// (replicate padding: min/max-neutral for the first erosion; row halos
// correct, deeper halo don't-care). Fully-OOB x-column items (only at
// bx==0 / bx==3, 8-aligned so never straddling) write +inf directly --
// each LDS address has exactly one writer, so no DMA/ds_write race.
__device__ __forceinline__ void fill_dma(uint* __restrict__ A, const f16* __restrict__ src,
                                         int tileX, int tileY, int tid) {
#pragma unroll
    for (int j = 0; j < 6; j++) {
        const int i = tid + 256 * j;
        if (i < FILLN) {
            const int r = i / 18;
            const int q = i - 18 * r;
            const int gy = tileY + r - 4;
            const int gx = tileX - 8 + 8 * q;
            if (gx < 0 || gx >= W) {
                *(uint4*)(A + 4 * i) = make_uint4(PINF2, PINF2, PINF2, PINF2);
            } else {
                const int gyc = min(max(gy, 0), H - 1);
                lds_dma16(A + 4 * i, src + (size_t)gyc * W + gx);
            }
        }
    }
}

// Stage 1: one skeletonize iteration A(fp16) -> B(fp16). 238 items =
// 14 strips(5 rows) x 17 groups(8 cols); rolling 3-row window.
template<bool EDGE>
__device__ void stage1(const uint* __restrict__ Au, uint* __restrict__ Bu,
                       int tileX, int tileY, int tid) {
    if (tid >= S1ITEMS) return;
    const int s = tid / TQ;
    const int g = tid - TQ * s;
    const int gcb = tileX + 8 * g - 4;   // global col of first output
    const int ys = tileY - 2 + 5 * s;    // global row of first output
    bool eok[6], wok[4];
    if (EDGE) {
#pragma unroll
        for (int i = 0; i < 6; i++) eok[i] = ((unsigned)(gcb - 2 + 2 * i) < (unsigned)W);
#pragma unroll
        for (int p = 0; p < 4; p++) wok[p] = ((unsigned)(gcb + 2 * p) < (unsigned)W);
    }
    const int lr = 5 * s + 2;
    const uint* Ab = Au + 4 * g;
    uint m[3][6], sc[3][4], hx[3][4], e[6], ec_cur[4], ec_nxt[4], tsc[4];
    hmin8p(Ab + (lr - 2) * APU, m[0], tsc);
    hmin8p(Ab + (lr - 1) * APU, m[1], tsc);
    hmin8p(Ab + (lr + 0) * APU, m[2], sc[0]);
    erode8<EDGE>(m[0], m[1], m[2], (unsigned)(ys - 1) < (unsigned)H, eok, e);
    hmax8(e, hx[0], ec_nxt);
    hmin8p(Ab + (lr + 1) * APU, m[0], sc[1]);
    erode8<EDGE>(m[1], m[2], m[0], (unsigned)ys < (unsigned)H, eok, e);
    hmax8(e, hx[1], ec_cur);
#pragma unroll
    for (int k = 0; k < 5; k++) {
        hmin8p(Ab + (lr + 2 + k) * APU, m[(k + 1) % 3], sc[(2 + k) % 3]);
        erode8<EDGE>(m[(k + 2) % 3], m[k % 3], m[(k + 1) % 3],
                     (unsigned)(ys + k + 1) < (unsigned)H, eok, e);
        hmax8(e, hx[(k + 2) % 3], ec_nxt);
        const int br = 5 * s + k;
        if (br < BROWS) {
            const bool rin = EDGE ? ((unsigned)(ys + k) < (unsigned)H) : true;
            uint o[4];
#pragma unroll
            for (int p = 0; p < 4; p++) {
                uint t = pmax(hx[k % 3][p], pmax(hx[(k + 1) % 3][p], hx[(k + 2) % 3][p]));
                uint v = upd_pair(sc[k % 3][p], ec_cur[p], t);
                o[p] = EDGE ? ((rin && wok[p]) ? v : PINF2) : v;
            }
            *(uint4*)(Bu + br * BPU + 4 * g) = make_uint4(o[0], o[1], o[2], o[3]);
        }
#pragma unroll
        for (int p = 0; p < 4; p++) ec_cur[p] = ec_nxt[p];
    }
}

// Stage 2: second iteration B(fp16) -> interior 64x128 (fp16 global or regs).
// 256 items = 16 groups(8 cols) x 16 strips(4 rows).
template<bool EDGE, bool TOREG>
__device__ void stage2(const uint* __restrict__ Bu, int tileX, int tileY, int tid,
                       f16* __restrict__ gdst, uint* __restrict__ oreg) {
    const int g = tid & 15;
    const int ty = tid >> 4;
    const int X = tileX + 8 * g;
    const int gy0 = tileY + 4 * ty;
    const int rb = 4 * ty + 2;
    bool eok[6];
    if (EDGE) {
#pragma unroll
        for (int i = 0; i < 6; i++) eok[i] = ((unsigned)(X - 2 + 2 * i) < (unsigned)W);
    }
    const uint* Bb = Bu + 4 * g;
    uint m[3][6], sc[3][4], hx[3][4], e[6], ec_cur[4], ec_nxt[4], tsc[4];
    hmin8p(Bb + (rb - 2) * BPU, m[0], tsc);
    hmin8p(Bb + (rb - 1) * BPU, m[1], tsc);
    hmin8p(Bb + (rb + 0) * BPU, m[2], sc[0]);
    erode8<EDGE>(m[0], m[1], m[2], (unsigned)(gy0 - 1) < (unsigned)H, eok, e);
    hmax8(e, hx[0], ec_nxt);
    hmin8p(Bb + (rb + 1) * BPU, m[0], sc[1]);
    erode8<EDGE>(m[1], m[2], m[0], true, eok, e);
    hmax8(e, hx[1], ec_cur);
#pragma unroll
    for (int k = 0; k < 4; k++) {
        hmin8p(Bb + (rb + 2 + k) * BPU, m[(k + 1) % 3], sc[(2 + k) % 3]);
        erode8<EDGE>(m[(k + 2) % 3], m[k % 3], m[(k + 1) % 3],
                     (unsigned)(gy0 + k + 1) < (unsigned)H, eok, e);
        hmax8(e, hx[(k + 2) % 3], ec_nxt);
        uint o[4];
#pragma unroll
        for (int p = 0; p < 4; p++) {
            uint t = pmax(hx[k % 3][p], pmax(hx[(k + 1) % 3][p], hx[(k + 2) % 3][p]));
            o[p] = upd_pair(sc[k % 3][p], ec_cur[p], t);
        }
        if (TOREG) {
#pragma unroll
            for (int p = 0; p < 4; p++) oreg[4 * k + p] = o[p];
        } else {
            *(uint4*)(gdst + (size_t)(gy0 + k) * W + X) = make_uint4(o[0], o[1], o[2], o[3]);
        }
#pragma unroll
        for (int p = 0; p < 4; p++) ec_cur[p] = ec_nxt[p];
    }
}

// ---- K1: sigmoid + dice partials (fused in fill) + iters 1,2 ----
__global__ __launch_bounds__(256, 4) void k_first(
    const float* __restrict__ logits, const float* __restrict__ target,
    f16* __restrict__ outb, float* __restrict__ parts0, float* __restrict__ parts1) {
    __shared__ __align__(16) uint A[AROWS * APU];
    __shared__ __align__(16) uint Bu[BROWS * BPU];
    __shared__ float red[8];
    const int img = blockIdx.z;
    const int tileX = blockIdx.x * 128, tileY = blockIdx.y * 64;
    const int tid = threadIdx.x;
    const bool pred = (img < NPRED);
    const bool edge = (blockIdx.x == 0) | (blockIdx.x == 3) |
                      (blockIdx.y == 0) | (blockIdx.y == 7);
    float2 ab;
    if (edge) {
        if (pred) ab = fillA_f32<true, 1>(A, logits + (size_t)img * IMG,
                                          target + (size_t)img * IMG, tileX, tileY, tid);
        else      ab = fillA_f32<true, 0>(A, target + (size_t)(img - NPRED) * IMG,
                                          nullptr, tileX, tileY, tid);
    } else {
        if (pred) ab = fillA_f32<false, 1>(A, logits + (size_t)img * IMG,
                                           target + (size_t)img * IMG, tileX, tileY, tid);
        else      ab = fillA_f32<false, 0>(A, target + (size_t)(img - NPRED) * IMG,
                                           nullptr, tileX, tileY, tid);
    }
    __syncthreads();
    float a = wsum64(ab.x), b = wsum64(ab.y);
    if ((tid & 63) == 0) { red[tid >> 6] = a; red[4 + (tid >> 6)] = b; }
    if (edge) stage1<true>(A, Bu, tileX, tileY, tid);
    else      stage1<false>(A, Bu, tileX, tileY, tid);
    __syncthreads();
    if (tid == 0) {
        int bi = blockIdx.z * 32 + blockIdx.y * 4 + blockIdx.x;
        parts0[bi] = red[0] + red[1] + red[2] + red[3];
        parts1[bi] = red[4] + red[5] + red[6] + red[7];
    }
    if (edge) stage2<true, false>(Bu, tileX, tileY, tid, outb + (size_t)img * IMG, nullptr);
    else      stage2<false, false>(Bu, tileX, tileY, tid, outb + (size_t)img * IMG, nullptr);
}

// ---- K2..K4: two iterations, fp16 buf -> fp16 buf. Two y-adjacent tiles per
// block; tile1's DMA fill issues after stage1(tile0) (A dead) and drains under
// stage2(tile0)'s LDS compute + global writes, hiding the HBM latency. ----
__global__ __launch_bounds__(256, 4) void k_mid(
    const f16* __restrict__ in, f16* __restrict__ outb) {
    __shared__ __align__(16) uint A[AROWS * APU];
    __shared__ __align__(16) uint Bu[BROWS * BPU];
    const int img = blockIdx.z;
    const int tileX = blockIdx.x * 128;
    const int by0 = blockIdx.y * 2;
    const int tY0 = by0 * 64, tY1 = tY0 + 64;
    const int tid = threadIdx.x;
    const f16* src = in + (size_t)img * IMG;
    f16* dst = outb + (size_t)img * IMG;
    const bool ex = (blockIdx.x == 0) | (blockIdx.x == 3);
    const bool e0 = ex | (by0 == 0);
    const bool e1 = ex | (by0 + 1 == 7);

    fill_dma(A, src, tileX, tY0, tid);
    __syncthreads();
    if (e0) stage1<true>(A, Bu, tileX, tY0, tid);
    else    stage1<false>(A, Bu, tileX, tY0, tid);
    __syncthreads();                       // all A-reads of tile0 retired
    fill_dma(A, src, tileX, tY1, tid);     // issue only; drains at next barrier
    if (e0) stage2<true, false>(Bu, tileX, tY0, tid, dst, nullptr);
    else    stage2<false, false>(Bu, tileX, tY0, tid, dst, nullptr);
    __syncthreads();                       // vmcnt(0): tile1 A ready; B-reads done
    if (e1) stage1<true>(A, Bu, tileX, tY1, tid);
    else    stage1<false>(A, Bu, tileX, tY1, tid);
    __syncthreads();
    if (e1) stage2<true, false>(Bu, tileX, tY1, tid, dst, nullptr);
    else    stage2<false, false>(Bu, tileX, tY1, tid, dst, nullptr);
}

// ---- K5: iters 9,10 for pred tile AND matching target tile; skel-dice
// partials. Target fill issues before stage2(pred) to overlap the DMA. ----
__global__ __launch_bounds__(256, 4) void k_last(
    const f16* __restrict__ in, float* __restrict__ pA,
    float* __restrict__ pB, float* __restrict__ pC) {
    __shared__ __align__(16) uint A[AROWS * APU];
    __shared__ __align__(16) uint Bu[BROWS * BPU];
    __shared__ float red[12];
    const int img = blockIdx.z;                  // 0..31
    const int tileX = blockIdx.x * 128, tileY = blockIdx.y * 64;
    const int tid = threadIdx.x;
    const bool edge = (blockIdx.x == 0) | (blockIdx.x == 3) |
                      (blockIdx.y == 0) | (blockIdx.y == 7);
    uint op[16], ot[16];
    fill_dma(A, in + (size_t)img * IMG, tileX, tileY, tid);
    __syncthreads();
    if (edge) stage1<true>(A, Bu, tileX, tileY, tid);
    else      stage1<false>(A, Bu, tileX, tileY, tid);
    __syncthreads();                              // A-reads retired
    fill_dma(A, in + (size_t)(img + NPRED) * IMG, tileX, tileY, tid);  // issue
    if (edge) stage2<true, true>(Bu, tileX, tileY, tid, nullptr, op);
    else      stage2<false, true>(Bu, tileX, tileY, tid, nullptr, op);
    __syncthreads();                              // target A ready; B-reads done
    if (edge) stage1<true>(A, Bu, tileX, tileY, tid);
    else      stage1<false>(A, Bu, tileX, tileY, tid);
    __syncthreads();
    if (edge) stage2<true, true>(Bu, tileX, tileY, tid, nullptr, ot);
    else      stage2<false, true>(Bu, tileX, tileY, tid, nullptr, ot);
    float a = 0.0f, b = 0.0f, c = 0.0f;
#pragma unroll
    for (int j = 0; j < 16; j++) {
        float2 p = unpack2(op[j]);
        float2 t = unpack2(ot[j]);
        a += p.x * t.x + p.y * t.y;
        b += p.x + p.y;
        c += t.x + t.y;
    }
    a = wsum64(a); b = wsum64(b); c = wsum64(c);
    if ((tid & 63) == 0) {
        red[tid >> 6] = a; red[4 + (tid >> 6)] = b; red[8 + (tid >> 6)] = c;
    }
    __syncthreads();
    if (tid == 0) {
        int bi = img * 32 + blockIdx.y * 4 + blockIdx.x;
        pA[bi] = red[0] + red[1] + red[2] + red[3];
        pB[bi] = red[4] + red[5] + red[6] + red[7];
        pC[bi] = red[8] + red[9] + red[10] + red[11];
    }
}

// ---- per-image dice from 32 tile partials (1 wave per image) ----
__global__ __launch_bounds__(64) void finalize_img(
    const float* __restrict__ parts0, const float* __restrict__ parts1,
    const float* __restrict__ pA, const float* __restrict__ pB,
    const float* __restrict__ pC, float* __restrict__ dices) {
    const int i = blockIdx.x, t = threadIdx.x;
    const bool v = (t < 32);
    float inter = wsum64(v ? parts0[i * 32 + t] : 0.0f);
    float sp = wsum64(v ? parts1[i * 32 + t] : 0.0f);
    float st = wsum64(v ? parts0[(NPRED + i) * 32 + t] : 0.0f);
    float i2 = wsum64(v ? pA[i * 32 + t] : 0.0f);
    float sp2 = wsum64(v ? pB[i * 32 + t] : 0.0f);
    float st2 = wsum64(v ? pC[i * 32 + t] : 0.0f);
    if (t == 0) {
        dices[i] = (float)((2.0 * (double)inter + 1e-5) / ((double)sp + (double)st + 1e-5));
        dices[32 + i] = (float)((2.0 * (double)i2 + 1e-5) / ((double)sp2 + (double)st2 + 1e-5));
    }
}

__global__ void finalize_out(const float* __restrict__ dices, float* __restrict__ out) {
    const int t = threadIdx.x;
    double d = 0.0, sd = 0.0;
    if (t < 32) { d = dices[t]; sd = dices[32 + t]; }
#pragma unroll
    for (int o = 32; o > 0; o >>= 1) { d += __shfl_down(d, o); sd += __shfl_down(sd, o); }
    if (t == 0) {
        d *= (1.0 / 32.0); sd *= (1.0 / 32.0);
        out[0] = (float)(0.5 * (1.0 - d) + 0.5 * (1.0 - sd));
        out[1] = (float)d;
        out[2] = (float)sd;
    }
}

extern "C" void kernel_launch(void* const* d_in, const int* in_sizes, int n_in,
                              void* d_out, int out_size, void* d_ws, size_t ws_size,
                              hipStream_t stream) {
    (void)in_sizes; (void)n_in; (void)out_size; (void)ws_size;
    const float* logits = (const float*)d_in[0];
    const float* target = (const float*)d_in[1];
    float* out = (float*)d_out;
    f16* buf0 = (f16*)d_ws;                         // 64*262144 halves (33.5 MB)
    f16* buf1 = buf0 + (size_t)NIMG * IMG;
    float* parts0 = (float*)(buf1 + (size_t)NIMG * IMG);   // 2048
    float* parts1 = parts0 + 2048;                  // 2048
    float* pA = parts1 + 2048;                      // 1024
    float* pB = pA + 1024;
    float* pC = pB + 1024;
    float* dices = pC + 1024;                       // 64

    dim3 blk(256, 1, 1);
    k_first<<<dim3(4, 8, NIMG), blk, 0, stream>>>(logits, target, buf0, parts0, parts1);
    k_mid<<<dim3(4, 4, NIMG), blk, 0, stream>>>(buf0, buf1);   // iters 3,4
    k_mid<<<dim3(4, 4, NIMG), blk, 0, stream>>>(buf1, buf0);   // iters 5,6
    k_mid<<<dim3(4, 4, NIMG), blk, 0, stream>>>(buf0, buf1);   // iters 7,8
    k_last<<<dim3(4, 8, NPRED), blk, 0, stream>>>(buf1, pA, pB, pC);  // iters 9,10 + partials
    finalize_img<<<32, 64, 0, stream>>>(parts0, parts1, pA, pB, pC, dices);
    finalize_out<<<1, 64, 0, stream>>>(dices, out);
}

// Round 5
// 220.854 us; speedup vs baseline: 1.0083x; 1.0083x over previous
//
#include <hip/hip_runtime.h>
#include <hip/hip_fp16.h>
#include <math.h>

// clDice loss on 32x1x512x512: sigmoid + dice + 10x soft-skeletonize + skel dice.
// R1: per-block partials (1059 -> 466 us). R3: fused 2 iters/kernel via LDS (485).
// R5: 256 thr/block (316). R7: fp16 ping-pong + fp16 LDS B (262).
// R9: packed fp16 stencil (v_pk_min/max) (265). R10: 8-px quantum + 64x128 tile (227).
// R11: DMA fill + batched MLP fill in k_first (220). R12: tile pairing: neutral ->
//      per-pass fixed cost dominates, not exposed fill drain.
// R13: FUSE 4 ITERS/PASS: 5 stencil passes -> 3 (2 + 4 + 4).
//      In-LDS chain A(halo8)->B(halo6)->C(halo4)->D(halo2)->out; each stage shifts
//      col-base by -4 so ALL ds_read_b128 stay 16B-aligned and the A fill (base
//      x0-16) keeps 16B-aligned global_load_lds. C aliases A's LDS, D aliases B's
//      => 49.3 KB, 3 blocks/CU. Stages 3,4 are the old stage1/stage2 verbatim
//      (pitches 72/68); numerics bit-identical to the unfused chain (masked-erode
//      SAME-pad equivalence holds at every depth). Kills 2 global round-trips
//      (134 MB) and 2 passes' fill+barrier+ramp overhead.

#define H 512
#define W 512
#define IMG (H * W)
#define NIMG 64
#define NPRED 32

// k_first (2-iter) geometry
#define APU 72      // A row pitch in uints; uint u <-> col tileX-8+2u
#define AROWS 74    // row r <-> gy = tileY + r - 4; data rows 0..71 (72,73 pad)
#define FILLN (AROWS * 18)
// final-stage input (old B / fused D): 68 rows x 68 uints; u <-> col tileX-4+2u
#define DPU 68
// fused 4-iter geometry
#define A4P 80      // A4: 80 data rows (gy = tileY+r-8), cols tileX-16+2u, u 0..79
#define A4R 82      // +2 pad rows for s1 rolling overread
#define B4P 76      // B4: 76 rows (gy = tileY+br-6), cols tileX-12+2u
#define C4P 72      // C4 (aliases A4): 72 rows (+2 pad overread), cols tileX-8+2u
#define FILL4N 1600 // 80 rows x 20 uint4-slots

#define PINF2 0x7C007C00u   // +inf,+inf (erosion-neutral pad)
#define NINF2 0xFC00FC00u   // -inf,-inf (dilation-neutral mask)
#define ONE2  0x3C003C00u   // 1.0,1.0

typedef _Float16 f16;
typedef _Float16 h2 __attribute__((ext_vector_type(2)));
typedef __fp16 fp16v2 __attribute__((ext_vector_type(2)));

__device__ __forceinline__ float2 unpack2(uint u) {
    fp16v2 h = __builtin_bit_cast(fp16v2, u);
    return make_float2((float)h.x, (float)h.y);
}
__device__ __forceinline__ uint pack2(float a, float b) {
    fp16v2 h = __builtin_amdgcn_cvt_pkrtz(a, b);
    return __builtin_bit_cast(uint, h);
}
__device__ __forceinline__ uint pmin(uint a, uint b) {
    uint d; asm("v_pk_min_f16 %0, %1, %2" : "=v"(d) : "v"(a), "v"(b)); return d;
}
__device__ __forceinline__ uint pmax(uint a, uint b) {
    uint d; asm("v_pk_max_f16 %0, %1, %2" : "=v"(d) : "v"(a), "v"(b)); return d;
}
// (hi<<16)|(lo>>16): odd-aligned fp16 pair from two even-aligned pairs
__device__ __forceinline__ uint abit(uint hi, uint lo) {
    return __builtin_amdgcn_alignbit(hi, lo, 16);
}

// async global->LDS DMA, 16B per lane (dest = wave-uniform base + lane*16).
__device__ __forceinline__ void lds_dma16(uint* l, const void* g) {
    __builtin_amdgcn_global_load_lds(
        (__attribute__((address_space(1))) void*)(g),
        (__attribute__((address_space(3))) void*)(l), 16, 0, 0);
}

__device__ __forceinline__ float wsum64(float v) {
#pragma unroll
    for (int o = 32; o > 0; o >>= 1) v += __shfl_down(v, o);
    return v;
}

// Horizontal 3-min at 6 aligned pairs (cols c0-2..c0+9) from 8 uints (cols
// c0-4..c0+11); p points at the uint of col c0-4 (16B-aligned by construction).
__device__ __forceinline__ void hmin8p(const uint* __restrict__ p, uint m[6], uint sc[4]) {
    uint4 w0 = *(const uint4*)(p);
    uint4 w1 = *(const uint4*)(p + 4);
    uint w[8] = {w0.x, w0.y, w0.z, w0.w, w1.x, w1.y, w1.z, w1.w};
    sc[0] = w[2]; sc[1] = w[3]; sc[2] = w[4]; sc[3] = w[5];
    uint s[7];
#pragma unroll
    for (int j = 0; j < 7; j++) s[j] = abit(w[j + 1], w[j]);
#pragma unroll
    for (int i = 0; i < 6; i++) m[i] = pmin(s[i], pmin(w[i + 1], s[i + 1]));
}

template<bool EDGE>
__device__ __forceinline__ void erode8(const uint a[6], const uint b[6], const uint c[6],
                                       bool rowok, const bool* eok, uint e[6]) {
#pragma unroll
    for (int i = 0; i < 6; i++) {
        uint v = pmin(a[i], pmin(b[i], c[i]));
        e[i] = EDGE ? ((rowok && eok[i]) ? v : NINF2) : v;
    }
}

__device__ __forceinline__ void hmax8(const uint e[6], uint hx[4], uint ec[4]) {
    uint a[5];
#pragma unroll
    for (int j = 0; j < 5; j++) a[j] = abit(e[j + 1], e[j]);
#pragma unroll
    for (int p = 0; p < 4; p++) {
        hx[p] = pmax(a[p], pmax(e[p + 1], a[p + 1]));
        ec[p] = e[p + 1];
    }
}

// skel update, packed fp16: o = clamp(s - (s-e)*t, 0, 1).
__device__ __forceinline__ uint upd_pair(uint s, uint ec, uint t) {
    h2 sh = __builtin_bit_cast(h2, s);
    h2 eh = __builtin_bit_cast(h2, ec);
    h2 th = __builtin_bit_cast(h2, t);
    h2 o = sh - (sh - eh) * th;
    return pmin(pmax(__builtin_bit_cast(uint, o), 0u), ONE2);
}

// Generic one-iteration stage: in(pitch PIN, rows <-> gy=tileY+r-RO-2, cols
// tileX-(2*RO+4)+2u) -> out(pitch POUT, rows <-> gy=tileY+br-RO, cols
// tileX-2*RO+2u). NG 8-col groups, NSTRIP strips of SROWS rows, NROWS outputs.
// All ds_read_b128 16B-aligned: p-index = 4g at every depth.
template<bool EDGE, int PIN, int POUT, int NG, int NSTRIP, int SROWS, int NROWS, int RO>
__device__ void stageN(const uint* __restrict__ in, uint* __restrict__ out,
                       int tileX, int tileY, int tid) {
    if (tid >= NSTRIP * NG) return;
    const int s = tid / NG;
    const int g = tid - NG * s;
    const int c0 = tileX - 2 * RO + 8 * g;   // global col of group's first output
    const int ys = tileY + SROWS * s - RO;   // global row of strip's first output
    bool eok[6], wok[4];
    if (EDGE) {
#pragma unroll
        for (int i = 0; i < 6; i++) eok[i] = ((unsigned)(c0 - 2 + 2 * i) < (unsigned)W);
#pragma unroll
        for (int p = 0; p < 4; p++) wok[p] = ((unsigned)(c0 + 2 * p) < (unsigned)W);
    }
    const int lr = SROWS * s + 2;
    const uint* Ab = in + 4 * g;
    uint m[3][6], sc[3][4], hx[3][4], e[6], ec_cur[4], ec_nxt[4], tsc[4];
    hmin8p(Ab + (lr - 2) * PIN, m[0], tsc);
    hmin8p(Ab + (lr - 1) * PIN, m[1], tsc);
    hmin8p(Ab + (lr + 0) * PIN, m[2], sc[0]);
    erode8<EDGE>(m[0], m[1], m[2], (unsigned)(ys - 1) < (unsigned)H, eok, e);
    hmax8(e, hx[0], ec_nxt);
    hmin8p(Ab + (lr + 1) * PIN, m[0], sc[1]);
    erode8<EDGE>(m[1], m[2], m[0], (unsigned)ys < (unsigned)H, eok, e);
    hmax8(e, hx[1], ec_cur);
#pragma unroll
    for (int k = 0; k < SROWS; k++) {
        hmin8p(Ab + (lr + 2 + k) * PIN, m[(k + 1) % 3], sc[(2 + k) % 3]);
        erode8<EDGE>(m[(k + 2) % 3], m[k % 3], m[(k + 1) % 3],
                     (unsigned)(ys + k + 1) < (unsigned)H, eok, e);
        hmax8(e, hx[(k + 2) % 3], ec_nxt);
        const int br = SROWS * s + k;
        if (NSTRIP * SROWS <= NROWS || br < NROWS) {   // constexpr-skipped when exact
            const bool rin = EDGE ? ((unsigned)(ys + k) < (unsigned)H) : true;
            uint o[4];
#pragma unroll
            for (int p = 0; p < 4; p++) {
                uint t = pmax(hx[k % 3][p], pmax(hx[(k + 1) % 3][p], hx[(k + 2) % 3][p]));
                uint v = upd_pair(sc[k % 3][p], ec_cur[p], t);
                o[p] = EDGE ? ((rin && wok[p]) ? v : PINF2) : v;
            }
            *(uint4*)(out + br * POUT + 4 * g) = make_uint4(o[0], o[1], o[2], o[3]);
        }
#pragma unroll
        for (int p = 0; p < 4; p++) ec_cur[p] = ec_nxt[p];
    }
}

// Final stage: D(fp16, pitch DPU) -> 64x128 interior (fp16 global or regs).
// 256 items = 16 groups(8 cols) x 16 strips(4 rows).
template<bool EDGE, bool TOREG>
__device__ void stage2(const uint* __restrict__ Du, int tileX, int tileY, int tid,
                       f16* __restrict__ gdst, uint* __restrict__ oreg) {
    const int g = tid & 15;
    const int ty = tid >> 4;
    const int X = tileX + 8 * g;
    const int gy0 = tileY + 4 * ty;
    const int rb = 4 * ty + 2;
    bool eok[6];
    if (EDGE) {
#pragma unroll
        for (int i = 0; i < 6; i++) eok[i] = ((unsigned)(X - 2 + 2 * i) < (unsigned)W);
    }
    const uint* Bb = Du + 4 * g;
    uint m[3][6], sc[3][4], hx[3][4], e[6], ec_cur[4], ec_nxt[4], tsc[4];
    hmin8p(Bb + (rb - 2) * DPU, m[0], tsc);
    hmin8p(Bb + (rb - 1) * DPU, m[1], tsc);
    hmin8p(Bb + (rb + 0) * DPU, m[2], sc[0]);
    erode8<EDGE>(m[0], m[1], m[2], (unsigned)(gy0 - 1) < (unsigned)H, eok, e);
    hmax8(e, hx[0], ec_nxt);
    hmin8p(Bb + (rb + 1) * DPU, m[0], sc[1]);
    erode8<EDGE>(m[1], m[2], m[0], true, eok, e);
    hmax8(e, hx[1], ec_cur);
#pragma unroll
    for (int k = 0; k < 4; k++) {
        hmin8p(Bb + (rb + 2 + k) * DPU, m[(k + 1) % 3], sc[(2 + k) % 3]);
        erode8<EDGE>(m[(k + 2) % 3], m[k % 3], m[(k + 1) % 3],
                     (unsigned)(gy0 + k + 1) < (unsigned)H, eok, e);
        hmax8(e, hx[(k + 2) % 3], ec_nxt);
        uint o[4];
#pragma unroll
        for (int p = 0; p < 4; p++) {
            uint t = pmax(hx[k % 3][p], pmax(hx[(k + 1) % 3][p], hx[(k + 2) % 3][p]));
            o[p] = upd_pair(sc[k % 3][p], ec_cur[p], t);
        }
        if (TOREG) {
#pragma unroll
            for (int p = 0; p < 4; p++) oreg[4 * k + p] = o[p];
        } else {
            *(uint4*)(gdst + (size_t)(gy0 + k) * W + X) = make_uint4(o[0], o[1], o[2], o[3]);
        }
#pragma unroll
        for (int p = 0; p < 4; p++) ec_cur[p] = ec_nxt[p];
    }
}

// Fill packed-fp16 LDS A (k_first geometry) from fp32 source (optional sigmoid);
// fuse dice partials over the 64x128 interior (fp32 pre-pack -> exact dice).
// Batched 2 x 3 load-then-store (MLP latency hiding).
template<bool EDGE, int SIG>
__device__ float2 fillA_f32(uint* __restrict__ A, const float* __restrict__ src,
                            const float* __restrict__ tgt,
                            int tileX, int tileY, int tid) {
    float a = 0.0f, b = 0.0f;
#pragma unroll
    for (int hf = 0; hf < 2; hf++) {
        float4 v0[3], v1[3], t0[3], t1[3];
        bool ld[3];
#pragma unroll
        for (int j = 0; j < 3; j++) {
            const int i = tid + 256 * (3 * hf + j);
            const int r = i / 18;
            const int q = i - 18 * r;
            const int gy = tileY + r - 4;
            const int gx = tileX - 8 + 8 * q;
            bool ok = (i < FILLN);
            if (EDGE) ok = ok && (r < 72) && ((unsigned)gy < (unsigned)H) &&
                           ((unsigned)gx < (unsigned)W);
            ld[j] = ok;
            if (ok) {
                const float* sp = src + (size_t)gy * W + gx;
                v0[j] = *(const float4*)(sp);
                v1[j] = *(const float4*)(sp + 4);
                if (SIG) {
                    const float* tp = tgt + (size_t)gy * W + gx;
                    t0[j] = *(const float4*)(tp);
                    t1[j] = *(const float4*)(tp + 4);
                }
            }
        }
#pragma unroll
        for (int j = 0; j < 3; j++) {
            const int i = tid + 256 * (3 * hf + j);
            const int r = i / 18;
            const int q = i - 18 * r;
            if (i < FILLN) {
                uint4 w = make_uint4(PINF2, PINF2, PINF2, PINF2);
                if (ld[j]) {
                    float4 f0 = v0[j], f1 = v1[j];
                    if (SIG) {
                        f0.x = 1.0f / (1.0f + __expf(-f0.x));
                        f0.y = 1.0f / (1.0f + __expf(-f0.y));
                        f0.z = 1.0f / (1.0f + __expf(-f0.z));
                        f0.w = 1.0f / (1.0f + __expf(-f0.w));
                        f1.x = 1.0f / (1.0f + __expf(-f1.x));
                        f1.y = 1.0f / (1.0f + __expf(-f1.y));
                        f1.z = 1.0f / (1.0f + __expf(-f1.z));
                        f1.w = 1.0f / (1.0f + __expf(-f1.w));
                    }
                    if (((unsigned)(r - 4) < 64u) && ((unsigned)(q - 1) < 16u)) {
                        if (SIG) {
                            a += f0.x * t0[j].x + f0.y * t0[j].y + f0.z * t0[j].z +
                                 f0.w * t0[j].w + f1.x * t1[j].x + f1.y * t1[j].y +
                                 f1.z * t1[j].z + f1.w * t1[j].w;
                            b += f0.x + f0.y + f0.z + f0.w + f1.x + f1.y + f1.z + f1.w;
                        } else {
                            a += f0.x + f0.y + f0.z + f0.w + f1.x + f1.y + f1.z + f1.w;
                        }
                    }
                    w.x = pack2(f0.x, f0.y); w.y = pack2(f0.z, f0.w);
                    w.z = pack2(f1.x, f1.y); w.w = pack2(f1.z, f1.w);
                }
                *(uint4*)(A + r * APU + 4 * q) = w;
            }
        }
    }
    return make_float2(a, b);
}

// DMA fill of A4 (fused geometry). Source rows clamped into the image
// (replicate = SAME-pad-equivalent through masked erosion); fully-OOB x-slots
// (8-aligned, never straddling) write +inf directly. Pad rows 80,81 untouched
// (read only by guarded-out strip-12 outputs).
__device__ __forceinline__ void fill_dma4(uint* __restrict__ A, const f16* __restrict__ src,
                                          int tileX, int tileY, int tid) {
#pragma unroll
    for (int j = 0; j < 7; j++) {
        const int i = tid + 256 * j;
        if (i < FILL4N) {
            const int r = i / 20;
            const int q = i - 20 * r;
            const int gy = tileY + r - 8;
            const int gx = tileX - 16 + 8 * q;
            if (gx < 0 || gx >= W) {
                *(uint4*)(A + r * A4P + 4 * q) = make_uint4(PINF2, PINF2, PINF2, PINF2);
            } else {
                const int gyc = min(max(gy, 0), H - 1);
                lds_dma16(A + r * A4P + 4 * q, src + (size_t)gyc * W + gx);
            }
        }
    }
}

// 4-iteration chain: A4 -> B4 -> C4(in A4) -> D(in B4) -> out.
// If PRE: issue the next tile's A4 DMA after s3's barrier (A4 dead; drains
// under s4's compute, retired by the caller's next __syncthreads()).
template<bool EDGE, bool TOREG, bool PRE>
__device__ void chain4(uint* __restrict__ A4, uint* __restrict__ B4,
                       int tileX, int tileY, int tid,
                       f16* __restrict__ dst, uint* __restrict__ oreg,
                       const f16* __restrict__ pre) {
    stageN<EDGE, A4P, B4P, 19, 13, 6, 76, 6>(A4, B4, tileX, tileY, tid);
    __syncthreads();
    stageN<EDGE, B4P, C4P, 18, 12, 6, 72, 4>(B4, A4, tileX, tileY, tid);
    __syncthreads();
    stageN<EDGE, C4P, DPU, 17, 14, 5, 68, 2>(A4, B4, tileX, tileY, tid);
    __syncthreads();
    if (PRE) fill_dma4(A4, pre, tileX, tileY, tid);
    stage2<EDGE, TOREG>(B4, tileX, tileY, tid, dst, oreg);
}

__device__ __forceinline__ bool is_edge() {
    return (blockIdx.x == 0) | (blockIdx.x == 3) | (blockIdx.y == 0) | (blockIdx.y == 7);
}

// ---- K1: sigmoid + dice partials (fused in fill) + iters 1,2 ----
__global__ __launch_bounds__(256, 4) void k_first(
    const float* __restrict__ logits, const float* __restrict__ target,
    f16* __restrict__ outb, float* __restrict__ parts0, float* __restrict__ parts1) {
    __shared__ __align__(16) uint A[AROWS * APU];
    __shared__ __align__(16) uint Bu[68 * DPU];
    __shared__ float red[8];
    const int img = blockIdx.z;
    const int tileX = blockIdx.x * 128, tileY = blockIdx.y * 64;
    const int tid = threadIdx.x;
    const bool pred = (img < NPRED);
    const bool edge = is_edge();
    float2 ab;
    if (edge) {
        if (pred) ab = fillA_f32<true, 1>(A, logits + (size_t)img * IMG,
                                          target + (size_t)img * IMG, tileX, tileY, tid);
        else      ab = fillA_f32<true, 0>(A, target + (size_t)(img - NPRED) * IMG,
                                          nullptr, tileX, tileY, tid);
    } else {
        if (pred) ab = fillA_f32<false, 1>(A, logits + (size_t)img * IMG,
                                           target + (size_t)img * IMG, tileX, tileY, tid);
        else      ab = fillA_f32<false, 0>(A, target + (size_t)(img - NPRED) * IMG,
                                           nullptr, tileX, tileY, tid);
    }
    __syncthreads();
    float a = wsum64(ab.x), b = wsum64(ab.y);
    if ((tid & 63) == 0) { red[tid >> 6] = a; red[4 + (tid >> 6)] = b; }
    if (edge) stageN<true, APU, DPU, 17, 14, 5, 68, 2>(A, Bu, tileX, tileY, tid);
    else      stageN<false, APU, DPU, 17, 14, 5, 68, 2>(A, Bu, tileX, tileY, tid);
    __syncthreads();
    if (tid == 0) {
        int bi = blockIdx.z * 32 + blockIdx.y * 4 + blockIdx.x;
        parts0[bi] = red[0] + red[1] + red[2] + red[3];
        parts1[bi] = red[4] + red[5] + red[6] + red[7];
    }
    if (edge) stage2<true, false>(Bu, tileX, tileY, tid, outb + (size_t)img * IMG, nullptr);
    else      stage2<false, false>(Bu, tileX, tileY, tid, outb + (size_t)img * IMG, nullptr);
}

// ---- K2: iters 3-6 in one pass, fp16 buf -> fp16 buf ----
__global__ __launch_bounds__(256, 3) void k_mid4(
    const f16* __restrict__ in, f16* __restrict__ outb) {
    __shared__ __align__(16) uint A4[A4R * A4P];
    __shared__ __align__(16) uint B4[76 * B4P];
    const int img = blockIdx.z;
    const int tileX = blockIdx.x * 128, tileY = blockIdx.y * 64;
    const int tid = threadIdx.x;
    const bool edge = is_edge();
    const f16* src = in + (size_t)img * IMG;
    f16* dst = outb + (size_t)img * IMG;
    fill_dma4(A4, src, tileX, tileY, tid);
    __syncthreads();
    if (edge) chain4<true, false, false>(A4, B4, tileX, tileY, tid, dst, nullptr, nullptr);
    else      chain4<false, false, false>(A4, B4, tileX, tileY, tid, dst, nullptr, nullptr);
}

// ---- K3: iters 7-10 for pred tile AND matching target tile; skel-dice partials.
// Target-tile DMA issues inside chain4 (after s3) to overlap with s4. ----
__global__ __launch_bounds__(256, 3) void k_last4(
    const f16* __restrict__ in, float* __restrict__ pA,
    float* __restrict__ pB, float* __restrict__ pC) {
    __shared__ __align__(16) uint A4[A4R * A4P];
    __shared__ __align__(16) uint B4[76 * B4P];
    __shared__ float red[12];
    const int img = blockIdx.z;                  // 0..31
    const int tileX = blockIdx.x * 128, tileY = blockIdx.y * 64;
    const int tid = threadIdx.x;
    const bool edge = is_edge();
    uint op[16], ot[16];
    const f16* tsrc = in + (size_t)(img + NPRED) * IMG;
    fill_dma4(A4, in + (size_t)img * IMG, tileX, tileY, tid);
    __syncthreads();
    if (edge) {
        chain4<true, true, true>(A4, B4, tileX, tileY, tid, nullptr, op, tsrc);
        __syncthreads();   // drain target DMA; all D-reads of pred retired
        chain4<true, true, false>(A4, B4, tileX, tileY, tid, nullptr, ot, nullptr);
    } else {
        chain4<false, true, true>(A4, B4, tileX, tileY, tid, nullptr, op, tsrc);
        __syncthreads();
        chain4<false, true, false>(A4, B4, tileX, tileY, tid, nullptr, ot, nullptr);
    }
    float a = 0.0f, b = 0.0f, c = 0.0f;
#pragma unroll
    for (int j = 0; j < 16; j++) {
        float2 p = unpack2(op[j]);
        float2 t = unpack2(ot[j]);
        a += p.x * t.x + p.y * t.y;
        b += p.x + p.y;
        c += t.x + t.y;
    }
    a = wsum64(a); b = wsum64(b); c = wsum64(c);
    if ((tid & 63) == 0) {
        red[tid >> 6] = a; red[4 + (tid >> 6)] = b; red[8 + (tid >> 6)] = c;
    }
    __syncthreads();
    if (tid == 0) {
        int bi = img * 32 + blockIdx.y * 4 + blockIdx.x;
        pA[bi] = red[0] + red[1] + red[2] + red[3];
        pB[bi] = red[4] + red[5] + red[6] + red[7];
        pC[bi] = red[8] + red[9] + red[10] + red[11];
    }
}

// ---- per-image dice from 32 tile partials (1 wave per image) ----
__global__ __launch_bounds__(64) void finalize_img(
    const float* __restrict__ parts0, const float* __restrict__ parts1,
    const float* __restrict__ pA, const float* __restrict__ pB,
    const float* __restrict__ pC, float* __restrict__ dices) {
    const int i = blockIdx.x, t = threadIdx.x;
    const bool v = (t < 32);
    float inter = wsum64(v ? parts0[i * 32 + t] : 0.0f);
    float sp = wsum64(v ? parts1[i * 32 + t] : 0.0f);
    float st = wsum64(v ? parts0[(NPRED + i) * 32 + t] : 0.0f);
    float i2 = wsum64(v ? pA[i * 32 + t] : 0.0f);
    float sp2 = wsum64(v ? pB[i * 32 + t] : 0.0f);
    float st2 = wsum64(v ? pC[i * 32 + t] : 0.0f);
    if (t == 0) {
        dices[i] = (float)((2.0 * (double)inter + 1e-5) / ((double)sp + (double)st + 1e-5));
        dices[32 + i] = (float)((2.0 * (double)i2 + 1e-5) / ((double)sp2 + (double)st2 + 1e-5));
    }
}

__global__ void finalize_out(const float* __restrict__ dices, float* __restrict__ out) {
    const int t = threadIdx.x;
    double d = 0.0, sd = 0.0;
    if (t < 32) { d = dices[t]; sd = dices[32 + t]; }
#pragma unroll
    for (int o = 32; o > 0; o >>= 1) { d += __shfl_down(d, o); sd += __shfl_down(sd, o); }
    if (t == 0) {
        d *= (1.0 / 32.0); sd *= (1.0 / 32.0);
        out[0] = (float)(0.5 * (1.0 - d) + 0.5 * (1.0 - sd));
        out[1] = (float)d;
        out[2] = (float)sd;
    }
}

extern "C" void kernel_launch(void* const* d_in, const int* in_sizes, int n_in,
                              void* d_out, int out_size, void* d_ws, size_t ws_size,
                              hipStream_t stream) {
    (void)in_sizes; (void)n_in; (void)out_size; (void)ws_size;
    const float* logits = (const float*)d_in[0];
    const float* target = (const float*)d_in[1];
    float* out = (float*)d_out;
    f16* buf0 = (f16*)d_ws;                         // 64*262144 halves (33.5 MB)
    f16* buf1 = buf0 + (size_t)NIMG * IMG;
    float* parts0 = (float*)(buf1 + (size_t)NIMG * IMG);   // 2048
    float* parts1 = parts0 + 2048;                  // 2048
    float* pA = parts1 + 2048;                      // 1024
    float* pB = pA + 1024;
    float* pC = pB + 1024;
    float* dices = pC + 1024;                       // 64

    dim3 blk(256, 1, 1);
    k_first<<<dim3(4, 8, NIMG), blk, 0, stream>>>(logits, target, buf0, parts0, parts1);
    k_mid4<<<dim3(4, 8, NIMG), blk, 0, stream>>>(buf0, buf1);         // iters 3-6
    k_last4<<<dim3(4, 8, NPRED), blk, 0, stream>>>(buf1, pA, pB, pC); // iters 7-10 + partials
    finalize_img<<<32, 64, 0, stream>>>(parts0, parts1, pA, pB, pC, dices);
    finalize_out<<<1, 64, 0, stream>>>(dices, out);
}